// Round 1
// baseline (153.801 us; speedup 1.0000x reference)
//
#include <hip/hip_runtime.h>

// VP_lattice reverse step, B = 2^20 rows.
// Key insight: SVD + einsum in the reference == sqrtm(A^T A) (symmetric polar
// factor). Computed in closed form (Franca 1989 / Cayley-Hamilton), fp64 for
// the 3x3 sqrtm (error is amplified by coef*scale/2 up to ~16x at t~999),
// fp32 elsewhere. Memory-bound target: ~143 MB traffic -> ~24 us floor.

#define NUM_STEPS 1000

__global__ __launch_bounds__(256) void vp_lattice_kernel(
    const float* __restrict__ lt,
    const float* __restrict__ pl0,
    const float* __restrict__ plat,
    const float* __restrict__ alpha_bars,
    const float* __restrict__ betas,
    const float* __restrict__ sigmas,
    const float* __restrict__ z_noise,
    const int*   __restrict__ t,
    float* __restrict__ out,
    int n)
{
    int i = blockIdx.x * blockDim.x + threadIdx.x;
    if (i >= n) return;

    // ---- load A (3x3, row-major), 9 scalar floats (36B/row, 4-aligned) ----
    size_t b9 = (size_t)i * 9;
    float af0 = plat[b9 + 0], af1 = plat[b9 + 1], af2 = plat[b9 + 2];
    float af3 = plat[b9 + 3], af4 = plat[b9 + 4], af5 = plat[b9 + 5];
    float af6 = plat[b9 + 6], af7 = plat[b9 + 7], af8 = plat[b9 + 8];

    double a00 = af0, a01 = af1, a02 = af2;
    double a10 = af3, a11 = af4, a12 = af5;
    double a20 = af6, a21 = af7, a22 = af8;

    // ---- M = A^T A (symmetric, PSD) ----
    double m00 = a00*a00 + a10*a10 + a20*a20;
    double m01 = a00*a01 + a10*a11 + a20*a21;
    double m02 = a00*a02 + a10*a12 + a20*a22;
    double m11 = a01*a01 + a11*a11 + a21*a21;
    double m12 = a01*a02 + a11*a12 + a21*a22;
    double m22 = a02*a02 + a12*a12 + a22*a22;

    // ---- invariants ----
    double I1   = m00 + m11 + m22;
    double trM2 = m00*m00 + m11*m11 + m22*m22
                + 2.0*(m01*m01 + m02*m02 + m12*m12);
    double II   = 0.5*(I1*I1 - trM2);
    double III  = m00*(m11*m22 - m12*m12)
                - m01*(m01*m22 - m12*m02)
                + m02*(m01*m12 - m11*m02);
    double k = I1*I1 - 3.0*II;   // = 0.5 * sum_{i<j} (mu_i - mu_j)^2  >= 0

    double u00, u01, u02, u11, u12, u22;
    if (k <= 1e-12 * I1 * I1) {
        // near-spherical (all eigenvalues ~equal): U = sqrt(I1/3) * Id
        double lam = sqrt(fmax(I1 * (1.0/3.0), 0.0));
        u00 = u11 = u22 = lam;
        u01 = u02 = u12 = 0.0;
    } else {
        // largest eigenvalue of M via trig formula
        double l   = I1*(I1*I1 - 4.5*II) + 13.5*III;
        double sqk = sqrt(k);
        double arg = l / (k * sqk);
        arg = fmin(fmax(arg, -1.0), 1.0);
        double phi  = acos(arg) * (1.0/3.0);        // in [0, pi/3]
        double mu1  = (I1 + 2.0*sqk*cos(phi)) * (1.0/3.0);
        mu1 = fmax(mu1, 0.0);
        double lam1  = sqrt(mu1);                    // largest sing. value
        double sqIII = sqrt(fmax(III, 0.0));
        // lam2 + lam3 = sqrt(I1 - mu1 + 2*lam2*lam3), lam2*lam3 = sqIII/lam1
        double rest = I1 - mu1 + 2.0*sqIII / fmax(lam1, 1e-150);
        double s23  = sqrt(fmax(rest, 0.0));
        double IU   = lam1 + s23;                    // tr(U)
        double IIU  = 0.5*(IU*IU - I1);              // II(U)  (tr(U^2)=I1)
        double IIIU = sqIII;                         // det(U)
        // Cayley-Hamilton: (M + IIU*Id) * U = IU*M + IIIU*Id
        // => U = adj(P) * N / det(P),  P = M + IIU*Id (sym), N = IU*M + IIIU*Id
        double p00 = m00 + IIU, p11 = m11 + IIU, p22 = m22 + IIU;
        double c00 = p11*p22 - m12*m12;
        double c01 = m02*m12 - m01*p22;
        double c02 = m01*m12 - p11*m02;
        double c11 = p00*p22 - m02*m02;
        double c12 = m01*m02 - p00*m12;
        double c22 = p00*p11 - m01*m01;
        double detP = p00*c00 + m01*c01 + m02*c02;   // >0 unless rank(M)<=1
        double inv  = 1.0 / fmax(detP, 1e-280);
        double n00 = IU*m00 + IIIU, n01 = IU*m01, n02 = IU*m02;
        double n11 = IU*m11 + IIIU, n12 = IU*m12, n22 = IU*m22 + IIIU;
        // U = adj(P)*N * inv; symmetric in exact arithmetic -> symmetrize
        u00 = (c00*n00 + c01*n01 + c02*n02) * inv;
        u11 = (c01*n01 + c11*n11 + c12*n12) * inv;
        u22 = (c02*n02 + c12*n12 + c22*n22) * inv;
        u01 = 0.5*((c00*n01 + c01*n11 + c02*n12) +
                   (c01*n00 + c11*n01 + c12*n02)) * inv;
        u02 = 0.5*((c00*n02 + c01*n12 + c02*n22) +
                   (c02*n00 + c12*n01 + c22*n02)) * inv;
        u12 = 0.5*((c01*n02 + c11*n12 + c12*n22) +
                   (c02*n01 + c12*n11 + c22*n12)) * inv;
    }

    // vec = [L00, L01, L02, L11, L12, L22]
    float v0 = (float)u00, v1 = (float)u01, v2 = (float)u02;
    float v3 = (float)u11, v4 = (float)u12, v5 = (float)u22;

    // ---- schedule gather (tables are 4KB, L1/L2 resident) ----
    int ti = t[i];
    float beta_t    = betas[ti];
    float beta_last = betas[NUM_STEPS - 1];          // betas[-2]
    float alpha     = 1.0f - fminf(beta_t, beta_last);
    float ab        = alpha_bars[ti];
    float sig       = sigmas[ti];
    float coef  = 1.0f / sqrtf(alpha + 1e-8f);
    float scale = (1.0f - alpha) / sqrtf(1.0f - ab + 1e-8f);
    float zgate = (ti > 1) ? 1.0f : 0.0f;

    // ---- elementwise over 6 components, float2-vectorized (rows 8-aligned) --
    size_t b6 = (size_t)i * 6;
    const float2* lt2 = reinterpret_cast<const float2*>(lt + b6);
    const float2* p02 = reinterpret_cast<const float2*>(pl0 + b6);
    const float2* zn2 = reinterpret_cast<const float2*>(z_noise + b6);
    float2* out2      = reinterpret_cast<float2*>(out + b6);

    float lv[6], pv[6], zv[6];
    float2 tmp;
    tmp = lt2[0]; lv[0] = tmp.x; lv[1] = tmp.y;
    tmp = lt2[1]; lv[2] = tmp.x; lv[3] = tmp.y;
    tmp = lt2[2]; lv[4] = tmp.x; lv[5] = tmp.y;
    tmp = p02[0]; pv[0] = tmp.x; pv[1] = tmp.y;
    tmp = p02[1]; pv[2] = tmp.x; pv[3] = tmp.y;
    tmp = p02[2]; pv[4] = tmp.x; pv[5] = tmp.y;
    tmp = zn2[0]; zv[0] = tmp.x; zv[1] = tmp.y;
    tmp = zn2[1]; zv[2] = tmp.x; zv[3] = tmp.y;
    tmp = zn2[2]; zv[4] = tmp.x; zv[5] = tmp.y;

    float vv[6] = {v0, v1, v2, v3, v4, v5};
    float ov[6];
#pragma unroll
    for (int c = 0; c < 6; ++c) {
        float lc = lv[c];
        float pn = lc - 0.5f * (vv[c] + pv[c]);       // predicted_noise
        ov[c] = coef * (lc - scale * pn) + sig * (zgate * zv[c]);
    }
    out2[0] = make_float2(ov[0], ov[1]);
    out2[1] = make_float2(ov[2], ov[3]);
    out2[2] = make_float2(ov[4], ov[5]);
}

extern "C" void kernel_launch(void* const* d_in, const int* in_sizes, int n_in,
                              void* d_out, int out_size, void* d_ws, size_t ws_size,
                              hipStream_t stream) {
    const float* lt         = (const float*)d_in[0];
    const float* pl0        = (const float*)d_in[1];
    const float* plat       = (const float*)d_in[2];
    const float* alpha_bars = (const float*)d_in[3];
    const float* betas      = (const float*)d_in[4];
    const float* sigmas     = (const float*)d_in[5];
    const float* z_noise    = (const float*)d_in[6];
    const int*   t          = (const int*)d_in[7];
    float* out = (float*)d_out;

    int n = in_sizes[0] / 6;   // B rows
    int block = 256;
    int grid = (n + block - 1) / block;
    vp_lattice_kernel<<<grid, block, 0, stream>>>(
        lt, pl0, plat, alpha_bars, betas, sigmas, z_noise, t, out, n);
}